// Round 4
// baseline (213.016 us; speedup 1.0000x reference)
//
#include <hip/hip_runtime.h>
#include <hip/hip_bf16.h>
#include <stdint.h>

// Problem constants
#define Bn 16
#define Ln 4096
#define KF 384   // IN_F
#define OF 384   // OUT_F

// GEMM tiling
#define BM 128
#define BN 128
#define BK 32

static constexpr float kScale = 0.051031036307982884f;  // 1/sqrt(384)

typedef __attribute__((ext_vector_type(4))) float f32x4;
typedef __attribute__((ext_vector_type(2))) float f32x2;
typedef __attribute__((ext_vector_type(8))) short short8;   // 8 bf16 (4 VGPR) MFMA A/B frag
typedef __attribute__((ext_vector_type(4))) float floatx4;  // MFMA C/D frag
typedef __attribute__((ext_vector_type(4))) unsigned int uint4v;
typedef __attribute__((ext_vector_type(2))) unsigned int uint2v;

__device__ __forceinline__ void gl_lds16(const void* g, void* l) {
  __builtin_amdgcn_global_load_lds(
      (const __attribute__((address_space(1))) unsigned int*)g,
      (__attribute__((address_space(3))) unsigned int*)l, 16, 0, 0);
}

// float -> bf16 bits, round-to-nearest-even (finite inputs only)
__device__ __forceinline__ unsigned int f2bf_bits(float f) {
  union { float f; unsigned int u; } v;
  v.f = f;
  return (v.u + 0x7FFFu + ((v.u >> 16) & 1u)) >> 16;
}
__device__ __forceinline__ unsigned int pack2bf(float lo, float hi) {
  return f2bf_bits(lo) | (f2bf_bits(hi) << 16);
}

// Kernel 1: wmod[b][o][k] = bf16( SCALE*weight[o][k]*y[b][k] * rsqrt(sum_k(.)^2 + eps) )
__global__ __launch_bounds__(256) void modw_kernel(const float* __restrict__ weight,
                                                   const float* __restrict__ y,
                                                   unsigned short* __restrict__ wmod) {
  int t = threadIdx.x;
  int wv = t >> 6, lane = t & 63;
  int row = blockIdx.x * 4 + wv;  // [0, Bn*OF)
  int b = row / OF, o = row % OF;
  const float* wr = weight + o * KF;
  const float* yr = y + b * KF;
  float vals[6];
  float ss = 0.f;
#pragma unroll
  for (int j = 0; j < 3; ++j) {
    int k = (lane + 64 * j) * 2;
    f32x2 wvv = *(const f32x2*)(wr + k);
    f32x2 yv = *(const f32x2*)(yr + k);
    float t0 = kScale * wvv[0] * yv[0];
    float t1 = kScale * wvv[1] * yv[1];
    vals[2 * j] = t0;
    vals[2 * j + 1] = t1;
    ss += t0 * t0 + t1 * t1;
  }
#pragma unroll
  for (int off = 32; off >= 1; off >>= 1) ss += __shfl_xor(ss, off, 64);
  float d = rsqrtf(ss + 1e-8f);
  unsigned short* orow = wmod + row * KF;
#pragma unroll
  for (int j = 0; j < 3; ++j) {
    int k = (lane + 64 * j) * 2;
    *(unsigned int*)(orow + k) = pack2bf(vals[2 * j] * d, vals[2 * j + 1] * d);
  }
}

// Kernel 2: transpose+convert: Xt[b][p][k] = bf16(Efou[b][k][p])
// 64x64 tile per block via LDS. Grid = Bn * (KF/64) * (Ln/64) = 6144.
__global__ __launch_bounds__(256) void tconv_kernel(const float* __restrict__ X,
                                                    unsigned short* __restrict__ Xt) {
  __shared__ unsigned short sT[64 * 72];  // [p][k], pad 72 for b128-aligned reads
  int bid = blockIdx.x;
  int b = bid / 384;
  int rem = bid % 384;
  int kt = rem >> 6;   // 0..5
  int pt = rem & 63;   // 0..63
  const float* src = X + b * (KF * Ln) + (kt * 64) * Ln + pt * 64;
  int t = threadIdx.x;
  int p0 = (t & 15) * 4;
  int kr0 = (t >> 4) * 4;
  f32x4 xv[4];
#pragma unroll
  for (int i = 0; i < 4; ++i) xv[i] = *(const f32x4*)(src + (kr0 + i) * Ln + p0);
#pragma unroll
  for (int j = 0; j < 4; ++j) {
    uint2v v;
    v[0] = pack2bf(xv[0][j], xv[1][j]);
    v[1] = pack2bf(xv[2][j], xv[3][j]);
    *(uint2v*)(&sT[(p0 + j) * 72 + kr0]) = v;
  }
  __syncthreads();
  unsigned short* dst = Xt + b * (Ln * KF) + (pt * 64) * KF + kt * 64;
#pragma unroll
  for (int s = 0; s < 2; ++s) {
    int slot = t + 256 * s;
    int p = slot >> 3, kseg = slot & 7;
    uint4v v = *(const uint4v*)(&sT[p * 72 + kseg * 8]);
    *(uint4v*)(dst + p * KF + kseg * 8) = v;
  }
}

// Kernel 3: out[b][o][p] = sum_k wmod[b][o][k] * Xt[b][p][k]  (both k-contiguous bf16)
// m97-style: both operands DMA'd via global_load_lds, BK=32 double-buffered,
// one barrier per chunk, 12 chunks. 32KB LDS -> 4-5 blocks/CU.
__global__ __launch_bounds__(256, 4) void gemm_kernel(const unsigned short* __restrict__ Xt,
                                                      const unsigned short* __restrict__ Wm,
                                                      float* __restrict__ out) {
  __shared__ unsigned short sA[2][BM * BK];  // [o][k]
  __shared__ unsigned short sX[2][BN * BK];  // [p][k]

  // XCD swizzle: 3 consecutive logical blocks (sharing X) -> same XCD
  int flat = blockIdx.x;                         // 0..1535
  int logical = (flat & 7) * 192 + (flat >> 3);  // bijection
  int mt = logical % 3;
  int nt = (logical / 3) & 31;
  int b = logical / 96;

  int t = threadIdx.x;
  int wave = t >> 6, lane = t & 63;
  int quad = lane >> 4;

  const unsigned short* Wb = Wm + (b * OF + mt * BM) * KF;
  const unsigned short* Xb = Xt + b * (Ln * KF) + (nt * BN) * KF;

  floatx4 acc[4][4] = {};

  // DMA addressing: 8KB buffer = 512 lane-slots of 16B; 2 insts/wave each.
  int so[2], srow[2], sks[2];
#pragma unroll
  for (int j = 0; j < 2; ++j) {
    int boff = (wave * 2 + j) * 1024 + lane * 16;  // byte offset in 8KB buffer
    so[j] = boff;
    srow[j] = boff >> 6;         // 64B per row (32 bf16)
    sks[j] = (boff & 63) >> 1;   // element offset within row
  }

  int arow = (wave >> 1) * 64 + (lane & 15);
  int brow = (wave & 1) * 64 + (lane & 15);
  int kq = quad * 8;

  // prologue: stage chunk 0
#pragma unroll
  for (int j = 0; j < 2; ++j) {
    gl_lds16(Wb + srow[j] * KF + sks[j], (char*)sA[0] + so[j]);
    gl_lds16(Xb + srow[j] * KF + sks[j], (char*)sX[0] + so[j]);
  }
  __syncthreads();

  for (int kc = 0; kc < 12; ++kc) {
    int cur = kc & 1;
    if (kc < 11) {
      int k0 = (kc + 1) * BK;
#pragma unroll
      for (int j = 0; j < 2; ++j) {
        gl_lds16(Wb + srow[j] * KF + k0 + sks[j], (char*)sA[cur ^ 1] + so[j]);
        gl_lds16(Xb + srow[j] * KF + k0 + sks[j], (char*)sX[cur ^ 1] + so[j]);
      }
    }
    short8 af[4], bf[4];
#pragma unroll
    for (int mi = 0; mi < 4; ++mi)
      af[mi] = *(const short8*)(&sA[cur][(arow + mi * 16) * BK + kq]);
#pragma unroll
    for (int ni = 0; ni < 4; ++ni)
      bf[ni] = *(const short8*)(&sX[cur][(brow + ni * 16) * BK + kq]);
#pragma unroll
    for (int mi = 0; mi < 4; ++mi)
#pragma unroll
      for (int ni = 0; ni < 4; ++ni)
        acc[mi][ni] = __builtin_amdgcn_mfma_f32_16x16x32_bf16(af[mi], bf[ni], acc[mi][ni], 0, 0, 0);
    __syncthreads();  // drains next-chunk DMA + all readers done with 'cur'
  }

  // epilogue: C/D layout col=lane&15, row=quad*4+r
  float* outb = out + (b * OF + mt * BM) * Ln + nt * BN;
  int col = lane & 15;
#pragma unroll
  for (int mi = 0; mi < 4; ++mi) {
    int ob = (wave >> 1) * 64 + mi * 16 + quad * 4;
#pragma unroll
    for (int ni = 0; ni < 4; ++ni) {
      int p = (wave & 1) * 64 + ni * 16 + col;
#pragma unroll
      for (int r = 0; r < 4; ++r) outb[(ob + r) * Ln + p] = acc[mi][ni][r];
    }
  }
}

extern "C" void kernel_launch(void* const* d_in, const int* in_sizes, int n_in,
                              void* d_out, int out_size, void* d_ws, size_t ws_size,
                              hipStream_t stream) {
  const float* Efou = (const float*)d_in[0];    // [B, L, IN_F] fp32 (raw: [B][KF][Ln])
  const float* y = (const float*)d_in[1];       // [B, IN_F] fp32
  const float* weight = (const float*)d_in[2];  // [1, OUT_F, IN_F] fp32
  float* out = (float*)d_out;                   // [B*OUT_F*Ln] fp32 (flat)
  unsigned short* wmod = (unsigned short*)d_ws;                         // 4.7 MB
  unsigned short* Xtr = (unsigned short*)((char*)d_ws + (8u << 20));    // 50.3 MB

  modw_kernel<<<(Bn * OF) / 4, 256, 0, stream>>>(weight, y, wmod);
  tconv_kernel<<<Bn * (KF / 64) * (Ln / 64), 256, 0, stream>>>(Efou, Xtr);
  gemm_kernel<<<Bn * (OF / BM) * (Ln / BN), 256, 0, stream>>>(Xtr, wmod, out);
}